// Round 5
// baseline (166.438 us; speedup 1.0000x reference)
//
#include <hip/hip_runtime.h>
#include <math.h>

#define NQ 12
#define DIM 4096
#define NL 6
#define TPB 128

// ---------------------------------------------------------------------------
// R13: R12 (verified correct) with the VGPR-spill fixed.
//
// R11/R12 post-mortem: __launch_bounds__(.., 2) makes the allocator cap at
// 128 VGPRs == sizeof(v[64]) alone -> everything else spilled to scratch
// (R12: WRITE_SIZE 34 MB, ~300 GB/s of pure spill traffic, VALUBusy 27%).
// R10 with arg2=1 allocated 136 VGPR spill-free. So: __launch_bounds__(TPB,1)
// and let HW occupancy fall out of VGPR (~3 waves/SIMD allowed) + LDS
// (5 blocks/CU) + grid (4 blocks/CU resident = 2 waves/SIMD).
//
// Structure (R12, correctness-verified): 2 waves/block, wave w = element
// b*2+w, R10's exact per-wave pipeline; one shared 32 KB LDS buffer,
// time-shared via token pattern:
//   bar; if(w==0) SESSION; bar; if(w==1) SESSION;
// Barriers at block scope (counts match); intra-session store->read ordering
// via the wave's own s_waitcnt lgkmcnt(0). One wave's DS session overlaps
// the other's register-only VALU phase; 4 blocks/CU fill remaining gaps.
// ---------------------------------------------------------------------------

// ---- d_ws layout (float offsets) — identical to R10 (prep verified) ----
#define WS_WA0 0        // 64 f2 : init lane factor e^{i(phi0_lane - pi/2*pop)}
#define WS_Z0  128      // 64 f2 : init reg  factor e^{i(phi0_hi  - pi/2*pop)}
#define WS_W   256      // 5*64 f2 : merged diag lane factor (post-T1 lane)
#define WS_Z   896      // 5*2*64 f2 : merged diag reg table [l][h][p]
#define WS_RYT 2176     // 72 float4 : (c,c,s,s) per (l,wire)

typedef float f2 __attribute__((ext_vector_type(2)));

static __device__ __forceinline__ f2 pk_mul(f2 a, f2 b) {
  f2 d; asm("v_pk_mul_f32 %0, %1, %2" : "=v"(d) : "v"(a), "v"(b)); return d;
}
static __device__ __forceinline__ f2 pk_fma(f2 a, f2 b, f2 c) {
  f2 d; asm("v_pk_fma_f32 %0, %1, %2, %3" : "=v"(d) : "v"(a), "v"(b), "v"(c)); return d;
}
// complex mul, both operands packed (re,im)
static __device__ __forceinline__ f2 cmulp(f2 a, f2 c) {
  f2 r1, d;
  asm("v_pk_mul_f32 %0, %1, %2 op_sel:[0,0] op_sel_hi:[0,1]"
      : "=v"(r1) : "v"(a), "v"(c));
  asm("v_pk_fma_f32 %0, %1, %2, %3 op_sel:[1,1,0] op_sel_hi:[1,0,1] neg_lo:[1,0,0]"
      : "=v"(d) : "v"(a), "v"(c), "v"(r1));
  return d;
}

// RY pair update over 64 regs: a' = c*a - s*b ; b' = s*a + c*b (R10-verified)
template<int BIT>
static __device__ __forceinline__ void apply_ry64(f2 v[64], f2 cc, f2 ss) {
  #pragma unroll
  for (int j = 0; j < 64; ++j) {
    if (j & (1 << BIT)) continue;
    const int k = j | (1 << BIT);
    f2 a = v[j], b = v[k];
    f2 t1 = pk_mul(a, cc);
    f2 t2 = pk_mul(a, ss);
    f2 na; asm("v_pk_fma_f32 %0, %1, %2, %3 neg_lo:[1,0,0] neg_hi:[1,0,0]"
               : "=v"(na) : "v"(b), "v"(ss), "v"(t1));
    f2 nb = pk_fma(b, cc, t2);
    v[j] = na; v[k] = nb;
  }
}

// ---------------------------------------------------------------------------
// Prep kernel — verbatim R10 (numerically verified by R10's passing run).
// ---------------------------------------------------------------------------
__global__ __launch_bounds__(256)
void qprep_kernel(const float* __restrict__ w, float* __restrict__ ws) {
  const int t = threadIdx.x;
  const float HPI = 1.57079632679489662f;

  if (t < 64) {              // WA0[u], u = label bits 0..5 <-> wires 11..6
    const int u = t;
    float f = 0.f;
    #pragma unroll
    for (int k = 0; k < 6; ++k) {
      float p = w[(0*NQ + (11-k))*3 + 0];
      f += ((u >> k) & 1) ? 0.5f*p : -0.5f*p;
    }
    f -= HPI * (float)__popc(u);
    float sv, cv; sincosf(f, &sv, &cv);
    ws[WS_WA0 + 2*u] = cv; ws[WS_WA0 + 2*u + 1] = sv;
  } else if (t < 128) {      // Z0[p], p = label bits 6..11 <-> wires 5..0
    const int p_ = t - 64;
    float f = 0.f;
    #pragma unroll
    for (int k = 0; k < 6; ++k) {
      float p = w[(0*NQ + (5-k))*3 + 0];
      f += ((p_ >> k) & 1) ? 0.5f*p : -0.5f*p;
    }
    f -= HPI * (float)__popc(p_);
    float sv, cv; sincosf(f, &sv, &cv);
    ws[WS_Z0 + 2*p_] = cv; ws[WS_Z0 + 2*p_ + 1] = sv;
  }

  // W[l][u], u = post-T1 lane = label bits 6..11 (u_k <-> wire 5-k)
  for (int idx = t; idx < 5*64; idx += 256) {
    const int l = idx >> 6, u = idx & 63;
    float f = 0.f;
    #pragma unroll
    for (int k = 0; k < 6; ++k) {
      float om = w[(l*NQ + (5-k))*3 + 2];
      f += ((u >> k) & 1) ? 0.5f*om : -0.5f*om;
    }
    const int gu = u ^ (u >> 1);
    #pragma unroll
    for (int k = 0; k < 6; ++k) {
      float ph = w[((l+1)*NQ + (5-k))*3 + 0];
      f += ((gu >> k) & 1) ? 0.5f*ph : -0.5f*ph;
    }
    float sv, cv; sincosf(f, &sv, &cv);
    ws[WS_W + 2*idx] = cv; ws[WS_W + 2*idx + 1] = sv;
  }

  // Z[l][h][p], p = label bits 0..5 (p_k <-> wire 11-k), h = lam6
  for (int idx = t; idx < 5*2*64; idx += 256) {
    const int l = idx >> 7, h = (idx >> 6) & 1, p_ = idx & 63;
    float f = 0.f;
    #pragma unroll
    for (int k = 0; k < 6; ++k) {
      float om = w[(l*NQ + (11-k))*3 + 2];
      f += ((p_ >> k) & 1) ? 0.5f*om : -0.5f*om;
    }
    const int gp = (p_ ^ (p_ >> 1)) ^ (h << 5);
    #pragma unroll
    for (int k = 0; k < 6; ++k) {
      float ph = w[((l+1)*NQ + (11-k))*3 + 0];
      f += ((gp >> k) & 1) ? 0.5f*ph : -0.5f*ph;
    }
    float sv, cv; sincosf(f, &sv, &cv);
    ws[WS_Z + 2*idx] = cv; ws[WS_Z + 2*idx + 1] = sv;
  }

  if (t < NL*NQ) {           // ryt: (c,c,s,s) of theta/2 per (l,wire)
    float sv, cv; sincosf(0.5f*w[t*3 + 1], &sv, &cv);
    ((float4*)(ws + WS_RYT))[t] = make_float4(cv, cv, sv, sv);
  }
}

// Buffer sessions — R10's exact address math. Intra-session ordering is the
// issuing wave's own lgkmcnt drain; compiler reordering pinned by "memory".
#define T1_SESSION() do {                                                    \
    _Pragma("unroll")                                                        \
    for (int m = 0; m < 32; ++m) {                                           \
      const int idx = (2*m) ^ (L & 62);                                      \
      *(float4*)(stb + L*512 + (idx << 3)) =                                 \
          make_float4(v[2*m].x, v[2*m].y, v[2*m+1].x, v[2*m+1].y);           \
    }                                                                        \
    asm volatile("s_waitcnt lgkmcnt(0)" ::: "memory");                       \
    _Pragma("unroll")                                                        \
    for (int p = 0; p < 64; ++p)                                             \
      v[p] = *(const f2*)(stb + p*512 + ((L ^ (p & 62)) << 3));              \
  } while (0)

#define FOLD_SESSION() do {                                                  \
    const int Gh  = (L ^ (L >> 1)) & 63;                                     \
    const int hb5 = (L & 1) << 5;                                            \
    const int gsw = Gh & 62;                                                 \
    _Pragma("unroll")                                                        \
    for (int m = 0; m < 32; ++m) {                                           \
      const int glo0 = ((2*m) ^ m) ^ hb5;                                    \
      const int e_ = glo0 & ~1;                                              \
      float4 q4;                                                             \
      if (m & 1) q4 = make_float4(v[2*m+1].x, v[2*m+1].y, v[2*m].x, v[2*m].y);\
      else       q4 = make_float4(v[2*m].x, v[2*m].y, v[2*m+1].x, v[2*m+1].y);\
      *(float4*)(stb + Gh*512 + ((e_ ^ gsw) << 3)) = q4;                     \
    }                                                                        \
    asm volatile("s_waitcnt lgkmcnt(0)" ::: "memory");                       \
    _Pragma("unroll")                                                        \
    for (int r = 0; r < 64; ++r)                                             \
      v[r] = *(const f2*)(stb + r*512 + ((L ^ (r & 62)) << 3));              \
  } while (0)

// ---------------------------------------------------------------------------
// Main kernel: 2 waves/block, one element per wave, shared 32 KB buffer.
// __launch_bounds__(TPB, 1): arg2>=2 caps VGPR at 128 == v[64] alone and
// spills everything else (R11/R12 post-mortem). arg2=1 -> ~136-160 VGPR,
// spill-free (R10-verified allocation regime).
// ---------------------------------------------------------------------------
__global__ __launch_bounds__(TPB, 1)
void qsim12_kernel(const float* __restrict__ x, const float* __restrict__ ws,
                   float* __restrict__ out) {
  __shared__ __align__(16) float st[2*DIM];   // 32768 B, time-shared
  const int L = threadIdx.x & 63;             // lane within wave
  const int w = threadIdx.x >> 6;             // wave id 0/1
  const int e = blockIdx.x*2 + w;             // batch element of this wave
  char* stb = (char*)st;

  // x cos/sin: lanes 0..11 compute, readlane broadcast (per wave).
  float csx[NQ], csy[NQ];
  {
    float xv = (L < NQ) ? x[e*NQ + L] : 0.f;
    float sv, cv; sincosf(0.5f*xv, &sv, &cv);
    #pragma unroll
    for (int q = 0; q < NQ; ++q) {
      csx[q] = __int_as_float(__builtin_amdgcn_readlane(__float_as_int(cv), q));
      csy[q] = __int_as_float(__builtin_amdgcn_readlane(__float_as_int(sv), q));
    }
  }

  f2 v[64];

  // ---- Init (A-storage, R10-verbatim): v[p]@lane L = element(hi=p, lo=L)
  {
    float rl = 1.f;
    #pragma unroll
    for (int k = 0; k < 6; ++k)
      rl *= ((L >> k) & 1) ? csy[11-k] : csx[11-k];
    float mlo[8], mhi[8];
    #pragma unroll
    for (int pm = 0; pm < 8; ++pm) {
      float a = ((pm >> 0) & 1) ? csy[5] : csx[5];
      a *= ((pm >> 1) & 1) ? csy[4] : csx[4];
      a *= ((pm >> 2) & 1) ? csy[3] : csx[3];
      mlo[pm] = a;
      float bb = ((pm >> 0) & 1) ? csy[2] : csx[2];
      bb *= ((pm >> 1) & 1) ? csy[1] : csx[1];
      bb *= ((pm >> 2) & 1) ? csy[0] : csx[0];
      mhi[pm] = bb;
    }
    const float2 wv = *(const float2*)(ws + WS_WA0 + 2*L);
    const f2 a0 = (f2){wv.x*rl, wv.y*rl};
    #pragma unroll
    for (int p = 0; p < 64; ++p) {
      const float2 zv = *(const float2*)(ws + WS_Z0 + 2*p);
      f2 ph = cmulp(a0, (f2){zv.x, zv.y});
      const float m = mlo[p & 7] * mhi[p >> 3];
      v[p] = pk_mul(ph, (f2){m, m});
    }
  }

  #define RY6(BIT, WQ) { const float4 r = *(const float4*)(ws + WS_RYT + 4*(l*NQ + (WQ))); \
      apply_ry64<BIT>(v, (f2){r.x, r.y}, (f2){r.z, r.w}); }

  #pragma unroll 1
  for (int l = 0; l < NL; ++l) {
    // h1: wires 5..0 (reg bits); entry state already in regs (init or FOLD)
    RY6(0,5) RY6(1,4) RY6(2,3) RY6(3,2) RY6(4,1) RY6(5,0)

    // T1 transpose, token-serialized on the shared buffer
    __syncthreads();                 // (1) prior sessions fully drained
    if (w == 0) T1_SESSION();
    __syncthreads();                 // (2) w0's reads done before w1's stores
    if (w == 1) T1_SESSION();        //     runs under w0's h2 below

    // h2: wires 11..6 (reg bits post-transpose)
    RY6(0,11) RY6(1,10) RY6(2,9) RY6(3,8) RY6(4,7) RY6(5,6)

    if (l < NL-1) {
      // merged diag D_om(l)*D_phi(l+1) at post-CNOT label gray(lambda)
      const float2 wv = *(const float2*)(ws + WS_W + (l*64 + L)*2);
      const f2 W = (f2){wv.x, wv.y};
      const float* zb = ws + WS_Z + ((l*2 + (L & 1))*64)*2;
      #pragma unroll
      for (int p0 = 0; p0 < 64; p0 += 8) {
        f2 z[8];
        #pragma unroll
        for (int q = 0; q < 8; ++q) {
          const float2 zv = *(const float2*)(zb + 2*(p0+q));
          z[q] = (f2){zv.x, zv.y};
        }
        #pragma unroll
        for (int q = 0; q < 8; ++q)
          v[p0+q] = cmulp(cmulp(v[p0+q], z[q]), W);
      }

      // fold-store + entry-load(l+1), token-serialized
      __syncthreads();               // (3)
      if (w == 0) FOLD_SESSION();
      __syncthreads();               // (4)
      if (w == 1) FOLD_SESSION();    //     runs under w0's next h1
    }
  }

  // ---- Epilogue (B-storage: lane = label bits 6..11), R10-verbatim.
  float ssum = 0.f;
  #pragma unroll
  for (int p = 0; p < 64; ++p)
    ssum += v[p].x*v[p].x + v[p].y*v[p].y;
  float s0 = ((L >> 5) & 1) ? -ssum : ssum;
  float s1 = (((L >> 4) ^ (L >> 5)) & 1) ? -ssum : ssum;
  #pragma unroll
  for (int off = 32; off >= 1; off >>= 1) {
    s0 += __shfl_down(s0, off);
    s1 += __shfl_down(s1, off);
  }
  if (L == 0) { out[e*2 + 0] = s0; out[e*2 + 1] = s1; }
}

extern "C" void kernel_launch(void* const* d_in, const int* in_sizes, int n_in,
                              void* d_out, int out_size, void* d_ws, size_t ws_size,
                              hipStream_t stream) {
  const float* x = (const float*)d_in[0];      // (B, 12) f32
  const float* w = (const float*)d_in[1];      // (6, 12, 3) f32
  float* out = (float*)d_out;                  // (B, 2) f32
  float* ws = (float*)d_ws;                    // needs >= 9856 B
  int B = in_sizes[0] / NQ;                    // B = 2048 (even)
  qprep_kernel<<<1, 256, 0, stream>>>(w, ws);
  qsim12_kernel<<<B/2, TPB, 0, stream>>>(x, ws, out);
}

// Round 8
// 125.078 us; speedup vs baseline: 1.3307x; 1.3307x over previous
//
#include <hip/hip_runtime.h>
#include <math.h>

#define NQ 12
#define DIM 4096
#define NL 6
#define TPB 256

// ---------------------------------------------------------------------------
// R15 (resubmit — previous round failed on container acquisition, kernel
// never ran): R14 with the lifting half-angle bug fixed.
//
// R14 post-mortem: the butterfly applies rotation [[c,-s],[s,c]] with
// c=cos(th/2), s=sin(th/2) (RY(th) has half-angle entries). Lifting coeffs
// for THAT rotation are s_lift = sin(th/2), w = (cos(th/2)-1)/sin(th/2)
// = -tan(th/4). R14 used sin(th) / -tan(th/2) — a rotation of 2x the angle
// (absmax 0.215). Fix is two prep lines; everything else R14-identical.
//
// Lifting: R = [[1,w],[0,1]]·[[1,0],[s,1]]·[[1,w],[0,1]]; butterfly
// a += w*b; b += s*a; a += w*b — 3 pk-FMA/pair vs 4. Exact identity:
//   b2 = s*a + (1+s*w)*b = s*a + c*b;  a2 = (1+w*s)*a + w*(1+c)*b
//   with w*(1+c) = (c^2-1)/s = -s  ->  a2 = c*a - s*b.   QED.
// RY work/layer 384 -> 288 pk per thread (-21% total VALU).
//
// Body (tables, diag merge, pass A/B/C addressing, gray-fold store, init,
// epilogue) is byte-identical to R9 (verified, 81us main / 129us bench).
// ---------------------------------------------------------------------------

// ---- d_ws table layout (float offsets) ----
#define WS_WA0 0      // 256 f2  : layer-0 D_phi thread factor e^{i fA0(t)}
#define WS_W   512    // 5*256 f2: merged D_om(l)*D_phi(l+1) thread factor
#define WS_ZA0 3072   // 16 f2   : layer-0 D_phi group factor (label bits 0-3)
#define WS_ZM  3104   // 5*2*16 f2: merged group factor, idx ((l*2+t7)*16+j)
#define WS_RYT 3424   // 72 float4: (w,w,s,s) per (l,wire)  [lifting coeffs]
#define WS_FLOATS 3712  // 14848 bytes total

typedef float f2 __attribute__((ext_vector_type(2)));

__device__ __forceinline__ f2 pk_mul(f2 a, f2 b) {
  f2 d; asm("v_pk_mul_f32 %0, %1, %2" : "=v"(d) : "v"(a), "v"(b)); return d;
}
__device__ __forceinline__ f2 pk_fma(f2 a, f2 b, f2 c) {
  f2 d; asm("v_pk_fma_f32 %0, %1, %2, %3" : "=v"(d) : "v"(a), "v"(b), "v"(c)); return d;
}
// complex mul, both operands packed (re,im)
__device__ __forceinline__ f2 cmulp(f2 a, f2 c) {
  f2 r1, d;
  asm("v_pk_mul_f32 %0, %1, %2 op_sel:[0,0] op_sel_hi:[0,1]"
      : "=v"(r1) : "v"(a), "v"(c));
  asm("v_pk_fma_f32 %0, %1, %2, %3 op_sel:[1,1,0] op_sel_hi:[1,0,1] neg_lo:[1,0,0]"
      : "=v"(d) : "v"(a), "v"(c), "v"(r1));
  return d;
}

// Lifting RY pair update: a += w*b; b += s*a; a += w*b
// == a' = c*a - s*b ; b' = s*a + c*b   (3 pk-FMA vs 4)
template<int BIT>
__device__ __forceinline__ void apply_ry16(f2 v[16], f2 ww, f2 ss) {
  #pragma unroll
  for (int j = 0; j < 16; ++j) {
    if (j & (1 << BIT)) continue;
    const int k = j | (1 << BIT);
    f2 a = v[j], b = v[k];
    a = pk_fma(b, ww, a);
    b = pk_fma(a, ss, b);
    a = pk_fma(b, ww, a);
    v[j] = a; v[k] = b;
  }
}

// ---------------------------------------------------------------------------
// Prep kernel: 1 block x 256 threads, fills d_ws from w. Runs once, ~2 us.
// w layout: w[(l*NQ + q)*3 + c], c: 0=phi, 1=theta, 2=omega.
// ---------------------------------------------------------------------------
__global__ __launch_bounds__(256)
void qprep_kernel(const float* __restrict__ w, float* __restrict__ ws) {
  const int t = threadIdx.x;

  // WA0[t] = e^{i * sum_k (t_k ? + : -) phi(0, 7-k)/2}   (label bit 4+k)
  {
    float f = 0.f;
    #pragma unroll
    for (int k = 0; k < 8; ++k) {
      float p = w[(0*NQ + 7 - k)*3 + 0];
      f += ((t >> k) & 1) ? 0.5f*p : -0.5f*p;
    }
    float sv, cv; sincosf(f, &sv, &cv);
    ws[WS_WA0 + 2*t] = cv; ws[WS_WA0 + 2*t + 1] = sv;
  }

  // W[l][t], l=0..4: omega(l) over t_k (label bit k <-> wire 11-k)
  //                + phi(l+1) over gray bits g_k = t_k^t_{k+1}, k=0..6
  #pragma unroll 1
  for (int l = 0; l < NL-1; ++l) {
    float f = 0.f;
    const int gt = t ^ (t >> 1);
    #pragma unroll
    for (int k = 0; k < 8; ++k) {
      float om = w[(l*NQ + 11 - k)*3 + 2];
      f += ((t >> k) & 1) ? 0.5f*om : -0.5f*om;
    }
    #pragma unroll
    for (int k = 0; k < 7; ++k) {
      float ph = w[((l+1)*NQ + 11 - k)*3 + 0];
      f += ((gt >> k) & 1) ? 0.5f*ph : -0.5f*ph;
    }
    float sv, cv; sincosf(f, &sv, &cv);
    ws[WS_W + (l*256 + t)*2] = cv; ws[WS_W + (l*256 + t)*2 + 1] = sv;
  }

  // zA0[j], j<16: phi(0) over j_m (label bit m <-> wire 11-m)
  if (t < 16) {
    float f = 0.f;
    #pragma unroll
    for (int m = 0; m < 4; ++m) {
      float p = w[(0*NQ + 11 - m)*3 + 0];
      f += ((t >> m) & 1) ? 0.5f*p : -0.5f*p;
    }
    float sv, cv; sincosf(f, &sv, &cv);
    ws[WS_ZA0 + 2*t] = cv; ws[WS_ZA0 + 2*t + 1] = sv;
  }

  // zM[l][h][j], idx = (l*2+h)*16+j, t<160:
  //   omega(l):  wires 3-m by j_m (label bits 8-11)
  //   phi(l+1):  g7 = h^j0 -> wire4; g8..g11 = (j^(j>>1)) bits 0..3 -> wires 3..0
  if (t < 160) {
    const int l = t >> 5, h = (t >> 4) & 1, j = t & 15;
    float f = 0.f;
    #pragma unroll
    for (int m = 0; m < 4; ++m) {
      float om = w[(l*NQ + 3 - m)*3 + 2];
      f += ((j >> m) & 1) ? 0.5f*om : -0.5f*om;
    }
    {
      float p4 = w[((l+1)*NQ + 4)*3 + 0];
      f += (h ^ (j & 1)) ? 0.5f*p4 : -0.5f*p4;
    }
    const int gj = j ^ (j >> 1);
    #pragma unroll
    for (int m = 0; m < 4; ++m) {
      float ph = w[((l+1)*NQ + 3 - m)*3 + 0];
      f += ((gj >> m) & 1) ? 0.5f*ph : -0.5f*ph;
    }
    float sv, cv; sincosf(f, &sv, &cv);
    ws[WS_ZM + 2*t] = cv; ws[WS_ZM + 2*t + 1] = sv;
  }

  // ryt[g], g<72: lifting coeffs of the HALF-ANGLE rotation:
  //   butterfly rotation angle is th/2  ->  s = sin(th/2), w = -tan(th/4)
  if (t < NL*NQ) {
    float th = w[t*3 + 1];
    float sv = sinf(0.5f*th);
    float wv = -tanf(0.25f*th);
    ((float4*)(ws + WS_RYT))[t] = make_float4(wv, wv, sv, sv);
  }
}

// ---------------------------------------------------------------------------
// Main kernel. LDS = 32768 B exactly -> 5 blocks/CU. (R9-verbatim body.)
// ---------------------------------------------------------------------------
__global__ __launch_bounds__(TPB, 5)
void qsim12_kernel(const float* __restrict__ x, const float* __restrict__ ws,
                   float* __restrict__ out) {
  __shared__ __align__(16) float st[2*DIM];   // 32 KB state (swizzled) ONLY

  const int t = threadIdx.x;
  const int b = blockIdx.x;
  char* stb = (char*)st;

  // x cos/sin: lanes 0-11 of each wave compute, readlane-broadcast to SGPRs.
  float csx[NQ], csy[NQ];
  {
    const int q = t & 63;
    float xv = (q < NQ) ? x[b*NQ + q] : 0.f;
    float sv, cv; sincosf(0.5f*xv, &sv, &cv);
    #pragma unroll
    for (int qq = 0; qq < NQ; ++qq) {
      csx[qq] = __int_as_float(__builtin_amdgcn_readlane(__float_as_int(cv), qq));
      csy[qq] = __int_as_float(__builtin_amdgcn_readlane(__float_as_int(sv), qq));
    }
  }

  // Precomputed byte-address bases (verified R5/R7 — unchanged).
  int baseA[8], baseB[8];
  #pragma unroll
  for (int m = 0; m < 8; ++m) {
    baseA[m] = (t << 7) + (((2*m) ^ (t & 14)) << 3);                 // phys14, A b128
    baseB[m] = ((t >> 4) << 11) + ((((t & 15) ^ (2*m))) << 3);       // + j*128
  }
  const int baseC = ((t >> 4) << 7) + ((((t & 15) ^ ((t >> 4) & 15))) << 3);  // + j*2048
  const int G = t ^ (t >> 1);
  int baseS[2];
  #pragma unroll
  for (int par = 0; par < 2; ++par) {
    const int k8 = par << 3;
    baseS[par] = ((((G >> 4) & 15) ^ k8) << 7)
               + ((((G & 15) ^ ((G >> 4) & 14) ^ k8)) << 3);
  }

  f2 v[16];

  // ---- Init: amp(label) = prod_w (bit? sin:cos) * (-i)^popcount(label).
  {
    float rhi = 1.f;
    #pragma unroll
    for (int k = 0; k < 8; ++k)
      rhi *= ((t >> k) & 1) ? csy[7-k] : csx[7-k];
    const int popt = __popc(t);
    #pragma unroll
    for (int j = 0; j < 16; ++j) {
      float r = rhi;
      #pragma unroll
      for (int m = 0; m < 4; ++m)
        r *= ((j >> m) & 1) ? csy[11-m] : csx[11-m];
      const int pj = (popt + __popc(j)) & 3;
      if      (pj == 0) v[j] = (f2){ r, 0.f};
      else if (pj == 1) v[j] = (f2){0.f, -r};
      else if (pj == 2) v[j] = (f2){-r, 0.f};
      else              v[j] = (f2){0.f,  r};
    }
  }

  #define RY(BIT, WQ)                                                     \
    { const float4 r = *(const float4*)(ws + WS_RYT + 4*(l*NQ + (WQ)));   \
      apply_ry16<BIT>(v, (f2){r.x, r.y}, (f2){r.z, r.w}); }

  #pragma unroll 1
  for (int l = 0; l < NL; ++l) {
    // ---- pass A: wires 11..8 (label bits 0..3)
    if (l > 0) {
      // diag for this boundary was already applied (merged) at pass C of l-1
      #pragma unroll
      for (int m = 0; m < 8; ++m) {
        float4 q4 = *(const float4*)(stb + baseA[m]);
        v[2*m]   = (f2){q4.x, q4.y};
        v[2*m+1] = (f2){q4.z, q4.w};
      }
    } else {
      // D_phi(0): group (label bits 0-3) table x thread factor
      const float2 wv = *(const float2*)(ws + WS_WA0 + 2*t);
      const f2 wA0 = (f2){wv.x, wv.y};
      #pragma unroll
      for (int j = 0; j < 16; ++j) {
        const float2 zv = *(const float2*)(ws + WS_ZA0 + 2*j);
        v[j] = cmulp(cmulp(v[j], (f2){zv.x, zv.y}), wA0);
      }
    }
    RY(0,11) RY(1,10) RY(2,9) RY(3,8)
    #pragma unroll
    for (int m = 0; m < 8; ++m)
      *(float4*)(stb + baseA[m]) =
          make_float4(v[2*m].x, v[2*m].y, v[2*m+1].x, v[2*m+1].y);
    __syncthreads();

    // ---- pass B: wires 7..4 (label bits 4..7); load phys14, store phys15
    #pragma unroll
    for (int m = 0; m < 8; ++m) {
      v[2*m]   = *(const f2*)(stb + baseB[m] + (2*m)*128);
      v[2*m+1] = *(const f2*)(stb + baseB[m] + (2*m+1)*128);
    }
    RY(0,7) RY(1,6) RY(2,5) RY(3,4)
    #pragma unroll
    for (int m = 0; m < 8; ++m) {
      *(f2*)(stb + baseB[m] + (2*m)*128)         = v[2*m];
      *(f2*)(stb + (baseB[m] ^ 8) + (2*m+1)*128) = v[2*m+1];
    }
    __syncthreads();

    // ---- pass C: wires 3..0 (label bits 8..11); load phys15
    #pragma unroll
    for (int j = 0; j < 16; ++j)
      v[j] = *(const f2*)(stb + baseC + j*2048);
    RY(0,3) RY(1,2) RY(2,1) RY(3,0)
    if (l < NL-1) {
      // merged diag: D_om(l) * D_phi(l+1) evaluated at post-CNOT label
      // gray(lambda). Group part zM[l][t7][j], thread part W[l][t].
      const float2 wv = *(const float2*)(ws + WS_W + (l*TPB + t)*2);
      const f2 W = (f2){wv.x, wv.y};
      const float* zmb = ws + WS_ZM + ((l*2 + ((t >> 7) & 1))*16)*2;
      #pragma unroll
      for (int j = 0; j < 16; ++j) {
        const float2 zv = *(const float2*)(zmb + 2*j);
        v[j] = cmulp(cmulp(v[j], (f2){zv.x, zv.y}), W);
      }
      // store with CNOT fold: slot = gray(label), layout phys14;
      // high nibble of gray(label) = gray4(j)
      #pragma unroll
      for (int j = 0; j < 16; ++j) {
        const int g4 = (j ^ (j >> 1)) & 15;
        *(f2*)(stb + baseS[j & 1] + (g4 << 11)) = v[j];
      }
      __syncthreads();
    }
  }

  // ---- Epilogue: labels s = t | j<<8; post-CNOT wire0 = j3, wire1 = j2^j3.
  float a0 = 0.f, a1 = 0.f;
  #pragma unroll
  for (int j = 0; j < 16; ++j) {
    float pr = v[j].x*v[j].x + v[j].y*v[j].y;
    a0 += ((j >> 3) & 1) ? -pr : pr;
    a1 += (((j >> 2) ^ (j >> 3)) & 1) ? -pr : pr;
  }
  #pragma unroll
  for (int off = 32; off >= 1; off >>= 1) {
    a0 += __shfl_down(a0, off);
    a1 += __shfl_down(a1, off);
  }
  __syncthreads();                 // all LDS reads done before st reuse
  if ((t & 63) == 0) { st[(t >> 6)*2] = a0; st[(t >> 6)*2 + 1] = a1; }
  __syncthreads();
  if (t == 0) {
    out[b*2 + 0] = st[0] + st[2] + st[4] + st[6];
    out[b*2 + 1] = st[1] + st[3] + st[5] + st[7];
  }
}

extern "C" void kernel_launch(void* const* d_in, const int* in_sizes, int n_in,
                              void* d_out, int out_size, void* d_ws, size_t ws_size,
                              hipStream_t stream) {
  const float* x = (const float*)d_in[0];      // (B, 12) f32
  const float* w = (const float*)d_in[1];      // (6, 12, 3) f32
  float* out = (float*)d_out;                  // (B, 2) f32
  float* ws = (float*)d_ws;                    // needs >= 14848 B
  int B = in_sizes[0] / NQ;
  qprep_kernel<<<1, 256, 0, stream>>>(w, ws);
  qsim12_kernel<<<B, TPB, 0, stream>>>(x, ws, out);
}